// Round 3
// baseline (846.825 us; speedup 1.0000x reference)
//
#include <hip/hip_runtime.h>
#include <hip/hip_bf16.h>

// ---------------------------------------------------------------------------
// TransformerBlock on MI355X (gfx950), bf16 MFMA pipeline. Round 2:
//  - GEMM: single-barrier double-buffered K-loop (BK=32, 2x8KB per matrix):
//    issue gl2lds(tile k+1) -> compute MFMA(tile k) -> barrier. The vmcnt(0)
//    drain at the barrier now lands AFTER a tile's worth of compute instead
//    of immediately after issue (R1 exposed full HBM latency every iter).
//  - XOR-swizzled LDS chunk layout (superrow = 2 rows = 8 chunks, XOR-8),
//    conflict-free b128 reads (R1 measured SQ_LDS_BANK_CONFLICT = 0).
//  - wT/qkvT: LDS 32x33 tiled transposes (R1 versions read at 6KB stride).
// ---------------------------------------------------------------------------

typedef __attribute__((ext_vector_type(8))) short bf16x8;
typedef __attribute__((ext_vector_type(4))) float f32x4;
typedef unsigned short u16;
typedef unsigned int u32;

#define MFMA16(a, b, c) __builtin_amdgcn_mfma_f32_16x16x32_bf16((a), (b), (c), 0, 0, 0)

__device__ __forceinline__ void gl2lds16(const void* g, void* l) {
  __builtin_amdgcn_global_load_lds((const __attribute__((address_space(1))) u32*)g,
                                   (__attribute__((address_space(3))) u32*)l, 16, 0, 0);
}

__device__ __forceinline__ u16 f2bf(float f) {
  __hip_bfloat16 h = __float2bfloat16(f);
  return *(u16*)&h;
}
__device__ __forceinline__ float bf2f(u16 u) {
  __hip_bfloat16 h;
  *(u16*)&h = u;
  return __bfloat162float(h);
}
__device__ __forceinline__ u32 pack2(float lo, float hi) {
  return (u32)f2bf(lo) | ((u32)f2bf(hi) << 16);
}

// Swizzled slot for chunk (row r, 16B-chunk c) of a 128x32 bf16 tile.
// Superrow = 2 rows = 8 chunks (128 B); XOR-8 within superrow.
__device__ __forceinline__ int sw_slot(int r, int c) {
  return (r >> 1) * 8 + ((((r & 1) << 2) | c) ^ ((r >> 1) & 7));
}

// ---------------------------------------------------------------------------
// GEMM: out[M][N] = A[M][K] (bf16) * Bt[N][K]^T (bf16)  [+bias] [relu] [+res]
// OUT_MODE: 0 = fp32 row-major, 1 = bf16 row-major, 2 = bf16 qkv slabs
// 1-D grid; XCD swizzle: xcd = bid&7 owns a contiguous M-chunk, n fastest.
// ---------------------------------------------------------------------------
template <int HAS_BIAS, int HAS_RES, int RELU, int OUT_MODE>
__global__ __launch_bounds__(256) void gemm_bt(const u16* __restrict__ A,
                                               const u16* __restrict__ Bt,
                                               const float* __restrict__ bias,
                                               const float* res, void* outp,
                                               int M, int N, int K, int gx) {
  __shared__ __attribute__((aligned(16))) u16 As[2][4096];
  __shared__ __attribute__((aligned(16))) u16 Bs[2][4096];
  const int bid = blockIdx.x;
  const int s = bid >> 3, xcd = bid & 7;
  const int gy8 = gridDim.x / (8 * gx);
  const int nI = s % gx, mC = s / gx;
  const int m0 = (xcd * gy8 + mC) * 128, n0 = nI * 128;
  const int w = threadIdx.x >> 6, l = threadIdx.x & 63;
  const int lm = l & 15, quad = l >> 4;
  const int wm = (w >> 1) * 64, wn = (w & 1) * 64;

  // This thread's two staging slots (per matrix): st0 = tid, st1 = tid+256.
  // Decode slot -> (row, chunk): R2 = st>>3, p = (st&7) ^ (R2&7).
  const int st0 = threadIdx.x, st1 = threadIdx.x + 256;
  int R2, p, ar0, ac0, ar1, ac1;
  R2 = st0 >> 3; p = (st0 & 7) ^ (R2 & 7); ar0 = 2 * R2 + (p >> 2); ac0 = p & 3;
  R2 = st1 >> 3; p = (st1 & 7) ^ (R2 & 7); ar1 = 2 * R2 + (p >> 2); ac1 = p & 3;
  const u16* Ag0 = A + (size_t)(m0 + ar0) * K + ac0 * 8;
  const u16* Ag1 = A + (size_t)(m0 + ar1) * K + ac1 * 8;
  const u16* Bg0 = Bt + (size_t)(n0 + ar0) * K + ac0 * 8;
  const u16* Bg1 = Bt + (size_t)(n0 + ar1) * K + ac1 * 8;
  // Wave-uniform LDS bases (gl2lds: base + lane*16).
  u16* La0 = &As[0][(w * 64) * 8];
  u16* La1 = &As[0][(256 + w * 64) * 8];
  u16* Lb0 = &Bs[0][(w * 64) * 8];
  u16* Lb1 = &Bs[0][(256 + w * 64) * 8];

  // Fragment LDS element offsets (constant across K).
  int afo[4], bfo[4];
#pragma unroll
  for (int i = 0; i < 4; ++i) afo[i] = sw_slot(wm + i * 16 + lm, quad) * 8;
#pragma unroll
  for (int j = 0; j < 4; ++j) bfo[j] = sw_slot(wn + j * 16 + lm, quad) * 8;

  f32x4 acc[4][4];
#pragma unroll
  for (int i = 0; i < 4; ++i)
#pragma unroll
    for (int j = 0; j < 4; ++j) acc[i][j] = 0.f;

  const int nk = K >> 5;
  // Prologue: stage tile 0 into buffer 0.
  gl2lds16(Ag0, La0);
  gl2lds16(Ag1, La1);
  gl2lds16(Bg0, Lb0);
  gl2lds16(Bg1, Lb1);
  __syncthreads();

  for (int k = 0; k < nk; ++k) {
    const int cb = k & 1;
    if (k + 1 < nk) {
      const int nb = cb ^ 1;
      const int go = (k + 1) * 32;
      gl2lds16(Ag0 + go, La0 + nb * 4096);
      gl2lds16(Ag1 + go, La1 + nb * 4096);
      gl2lds16(Bg0 + go, Lb0 + nb * 4096);
      gl2lds16(Bg1 + go, Lb1 + nb * 4096);
    }
    bf16x8 af[4], bfb[4];
#pragma unroll
    for (int i = 0; i < 4; ++i) af[i] = *(const bf16x8*)&As[cb][afo[i]];
#pragma unroll
    for (int j = 0; j < 4; ++j) bfb[j] = *(const bf16x8*)&Bs[cb][bfo[j]];
#pragma unroll
    for (int i = 0; i < 4; ++i)
#pragma unroll
      for (int j = 0; j < 4; ++j) acc[i][j] = MFMA16(af[i], bfb[j], acc[i][j]);
    __syncthreads();
  }

  // Epilogue. C/D layout (m89-verified): col = lane&15, row = quad*4 + reg.
#pragma unroll
  for (int i = 0; i < 4; ++i) {
#pragma unroll
    for (int j = 0; j < 4; ++j) {
      int col = n0 + wn + j * 16 + lm;
      float bs = HAS_BIAS ? bias[col] : 0.f;
#pragma unroll
      for (int r = 0; r < 4; ++r) {
        int row = m0 + wm + i * 16 + quad * 4 + r;
        float v = acc[i][j][r] + bs;
        if (RELU) v = fmaxf(v, 0.f);
        if (HAS_RES) v += res[(size_t)row * N + col];
        if (OUT_MODE == 0) {
          ((float*)outp)[(size_t)row * N + col] = v;
        } else if (OUT_MODE == 1) {
          ((u16*)outp)[(size_t)row * N + col] = f2bf(v);
        } else {  // qkv slab layout [sel*6+h][BT][64]
          int sel = col / 384;
          int rem = col - sel * 384;
          int hh = rem >> 6, dd = rem & 63;
          ((u16*)outp)[((size_t)(sel * 6 + hh) * 65536 + row) * 64 + dd] = f2bf(v);
        }
      }
    }
  }
}

// ---------------------------------------------------------------------------
// LayerNorm: one wave per 384-elem row, 4 rows per block, 6 elems/lane.
// ---------------------------------------------------------------------------
__global__ __launch_bounds__(256) void ln_kernel(const float* __restrict__ x,
                                                 const float* __restrict__ g,
                                                 const float* __restrict__ be,
                                                 u16* __restrict__ out) {
  int row = blockIdx.x * 4 + (threadIdx.x >> 6);
  int l = threadIdx.x & 63;
  const float2* xr = (const float2*)(x + (size_t)row * 384 + l * 6);
  float2 t0 = xr[0], t1 = xr[1], t2 = xr[2];
  float v[6] = {t0.x, t0.y, t1.x, t1.y, t2.x, t2.y};
  float s = 0.f;
#pragma unroll
  for (int i = 0; i < 6; ++i) s += v[i];
#pragma unroll
  for (int o = 1; o < 64; o <<= 1) s += __shfl_xor(s, o, 64);
  float mu = s * (1.f / 384.f);
  float var = 0.f;
#pragma unroll
  for (int i = 0; i < 6; ++i) {
    float d = v[i] - mu;
    var += d * d;
  }
#pragma unroll
  for (int o = 1; o < 64; o <<= 1) var += __shfl_xor(var, o, 64);
  float rs = rsqrtf(var * (1.f / 384.f) + 1e-5f);
  const float2* gg = (const float2*)(g + l * 6);
  const float2* bb = (const float2*)(be + l * 6);
  float2 g0 = gg[0], g1 = gg[1], g2 = gg[2];
  float2 b0 = bb[0], b1 = bb[1], b2 = bb[2];
  float gv[6] = {g0.x, g0.y, g1.x, g1.y, g2.x, g2.y};
  float bv[6] = {b0.x, b0.y, b1.x, b1.y, b2.x, b2.y};
  float o_[6];
#pragma unroll
  for (int i = 0; i < 6; ++i) o_[i] = (v[i] - mu) * rs * gv[i] + bv[i];
  u32* orow = (u32*)(out + (size_t)row * 384 + l * 6);
  orow[0] = pack2(o_[0], o_[1]);
  orow[1] = pack2(o_[2], o_[3]);
  orow[2] = pack2(o_[4], o_[5]);
}

// ---------------------------------------------------------------------------
// Coalesced transposes via LDS 32x33 tiles (fp32 -> bf16).
// wT: in [K][N] row-major -> out [N][K]. Grid (N/32, K/32), block 256.
// ---------------------------------------------------------------------------
__global__ __launch_bounds__(256) void wT_kernel(const float* __restrict__ in,
                                                 u16* __restrict__ out, int K,
                                                 int N) {
  __shared__ float tile[32][33];
  int n0 = blockIdx.x * 32, k0 = blockIdx.y * 32;
  int tx = threadIdx.x & 31, ty = threadIdx.x >> 5;
#pragma unroll
  for (int i = 0; i < 4; ++i)
    tile[ty + i * 8][tx] = in[(size_t)(k0 + ty + i * 8) * N + n0 + tx];
  __syncthreads();
#pragma unroll
  for (int i = 0; i < 4; ++i)
    out[(size_t)(n0 + ty + i * 8) * K + k0 + tx] = f2bf(tile[tx][ty + i * 8]);
}

// qkvT: W [6][384][64] -> out [(h*64+d)][384]. Grid (2, 12, 6), block 256.
__global__ __launch_bounds__(256) void qkvT_kernel(const float* __restrict__ W,
                                                   u16* __restrict__ out) {
  __shared__ float tile[32][33];
  int h = blockIdx.z;
  const float* in = W + (size_t)h * 384 * 64;
  u16* o = out + (size_t)h * 64 * 384;
  int n0 = blockIdx.x * 32, k0 = blockIdx.y * 32;
  int tx = threadIdx.x & 31, ty = threadIdx.x >> 5;
#pragma unroll
  for (int i = 0; i < 4; ++i)
    tile[ty + i * 8][tx] = in[(size_t)(k0 + ty + i * 8) * 64 + n0 + tx];
  __syncthreads();
#pragma unroll
  for (int i = 0; i < 4; ++i)
    o[(size_t)(n0 + ty + i * 8) * 384 + k0 + tx] = f2bf(tile[tx][ty + i * 8]);
}

// ---------------------------------------------------------------------------
// Attention. qkv slabs: Q = slab h, K = slab 6+h, V = slab 12+h, each
// [65536][64]. One merged kernel, TQ = blockIdx.x.
// ---------------------------------------------------------------------------
template <int TQ>
__device__ __forceinline__ void attn_body(const u16* __restrict__ qkv,
                                          u16* __restrict__ attnout,
                                          unsigned char* smx) {
  constexpr int NFULL = (TQ + 1) * 64;  // causal: cols 0..NFULL-1
  constexpr int NJ = NFULL / 16;
  constexpr int KSTEPS = NFULL / 32;
  int bh = blockIdx.y;
  int h = bh % 6, b = bh / 6;
  int tid = threadIdx.x;
  int w = tid >> 6, l = tid & 63;
  int lm = l & 15, quad = l >> 4;

  u16* Qs = (u16*)smx;            // [64][72]   phase 1
  u16* Ks = (u16*)(smx + 9216);   // [256][72]  phase 1
  u16* P = (u16*)smx;             // [64][256]  phase 2 (aliases Qs + Ks head)
  u16* Vt = (u16*)(smx + 32768);  // [64][256]  phase 2 (aliases Ks tail)

  const u16* Qg = qkv + ((size_t)h * 65536 + b * 256 + TQ * 64) * 64;
  const u16* Kg = qkv + ((size_t)(6 + h) * 65536 + b * 256) * 64;
  const u16* Vg = qkv + ((size_t)(12 + h) * 65536 + b * 256) * 64;

  for (int i = tid; i < 64 * 8; i += 256) {
    int r = i >> 3, cs = i & 7;
    *(bf16x8*)&Qs[r * 72 + cs * 8] = *(const bf16x8*)&Qg[r * 64 + cs * 8];
  }
  for (int i = tid; i < NFULL * 8; i += 256) {
    int r = i >> 3, cs = i & 7;
    *(bf16x8*)&Ks[r * 72 + cs * 8] = *(const bf16x8*)&Kg[r * 64 + cs * 8];
  }
  __syncthreads();

  // S = Q K^T ; wave w owns query rows [w*16, w*16+16).
  f32x4 sacc[NJ];
#pragma unroll
  for (int jt = 0; jt < NJ; ++jt) sacc[jt] = 0.f;
#pragma unroll
  for (int kk = 0; kk < 2; ++kk) {
    bf16x8 aq = *(const bf16x8*)&Qs[(w * 16 + lm) * 72 + kk * 32 + quad * 8];
#pragma unroll
    for (int jt = 0; jt < NJ; ++jt) {
      bf16x8 bk = *(const bf16x8*)&Ks[(jt * 16 + lm) * 72 + kk * 32 + quad * 8];
      sacc[jt] = MFMA16(aq, bk, sacc[jt]);
    }
  }
  __syncthreads();  // Qs/Ks reads done; P/Vt writes may begin.

  // Softmax in registers; 1/sqrt(64) folded into the exp argument.
  int trow = TQ * 64 + w * 16 + quad * 4;
  float inv_l[4];
#pragma unroll
  for (int reg = 0; reg < 4; ++reg) {
    float m_ = -3.0e38f;
#pragma unroll
    for (int jt = 0; jt < NJ; ++jt) {
      int col = jt * 16 + lm;
      if (col <= trow + reg) m_ = fmaxf(m_, sacc[jt][reg]);
    }
#pragma unroll
    for (int o = 1; o < 16; o <<= 1) m_ = fmaxf(m_, __shfl_xor(m_, o, 16));
    float s_ = 0.f;
#pragma unroll
    for (int jt = 0; jt < NJ; ++jt) {
      int col = jt * 16 + lm;
      float pv = (col <= trow + reg) ? __expf(0.125f * (sacc[jt][reg] - m_)) : 0.f;
      sacc[jt][reg] = pv;
      s_ += pv;
    }
#pragma unroll
    for (int o = 1; o < 16; o <<= 1) s_ += __shfl_xor(s_, o, 16);
    inv_l[reg] = 1.f / s_;
  }
#pragma unroll
  for (int jt = 0; jt < NJ; ++jt) {
#pragma unroll
    for (int reg = 0; reg < 4; ++reg) {
      int m = w * 16 + quad * 4 + reg;
      int col = jt * 16 + lm;
      P[m * 256 + (col ^ ((m & 7) * 8))] = f2bf(sacc[jt][reg] * inv_l[reg]);
    }
  }
  for (int i = tid; i < NFULL * 8; i += 256) {
    int sr = i >> 3, cs = i & 7;
    bf16x8 vv = *(const bf16x8*)&Vg[sr * 64 + cs * 8];
#pragma unroll
    for (int j = 0; j < 8; ++j) {
      int d = cs * 8 + j;
      Vt[d * 256 + (sr ^ ((d & 7) * 8))] = (u16)vv[j];
    }
  }
  __syncthreads();

  // O = P V.
  f32x4 oacc[4];
#pragma unroll
  for (int jt = 0; jt < 4; ++jt) oacc[jt] = 0.f;
#pragma unroll
  for (int ks = 0; ks < KSTEPS; ++ks) {
    int m = w * 16 + lm;
    int kc = ks * 32 + quad * 8;
    bf16x8 ap = *(const bf16x8*)&P[m * 256 + (kc ^ ((m & 7) * 8))];
#pragma unroll
    for (int jt = 0; jt < 4; ++jt) {
      int n = jt * 16 + lm;
      bf16x8 bv = *(const bf16x8*)&Vt[n * 256 + (kc ^ ((n & 7) * 8))];
      oacc[jt] = MFMA16(ap, bv, oacc[jt]);
    }
  }
  u16* Og = attnout + ((size_t)(b * 256 + TQ * 64)) * 384 + h * 64;
#pragma unroll
  for (int jt = 0; jt < 4; ++jt)
#pragma unroll
    for (int r = 0; r < 4; ++r)
      Og[(size_t)(w * 16 + quad * 4 + r) * 384 + jt * 16 + lm] = f2bf(oacc[jt][r]);
}

__global__ __launch_bounds__(256) void attn_all(const u16* __restrict__ qkv,
                                                u16* __restrict__ attnout) {
  __shared__ __attribute__((aligned(16))) unsigned char smx[65536];
  switch (blockIdx.x) {
    case 0: attn_body<0>(qkv, attnout, smx); break;
    case 1: attn_body<1>(qkv, attnout, smx); break;
    case 2: attn_body<2>(qkv, attnout, smx); break;
    default: attn_body<3>(qkv, attnout, smx); break;
  }
}

// ---------------------------------------------------------------------------
extern "C" void kernel_launch(void* const* d_in, const int* in_sizes, int n_in,
                              void* d_out, int out_size, void* d_ws, size_t ws_size,
                              hipStream_t stream) {
  const float* x = (const float*)d_in[0];
  const float* Wq = (const float*)d_in[1];
  const float* Wk = (const float*)d_in[2];
  const float* Wv = (const float*)d_in[3];
  const float* Wp = (const float*)d_in[4];
  const float* bp = (const float*)d_in[5];
  const float* W1 = (const float*)d_in[6];
  const float* b1 = (const float*)d_in[7];
  const float* W2 = (const float*)d_in[8];
  const float* b2 = (const float*)d_in[9];
  const float* g1 = (const float*)d_in[10];
  const float* be1 = (const float*)d_in[11];
  const float* g2 = (const float*)d_in[12];
  const float* be2 = (const float*)d_in[13];
  float* out = (float*)d_out;

  const int BT = 65536;  // 256*256
  char* ws = (char*)d_ws;
  u16* qkv = (u16*)(ws);                  // 18 slabs [BT][64] = 150,994,944 B
  u16* attnout = (u16*)(ws + 150994944);  // [BT][384]  bf16   50,331,648 B
  u16* ff1 = (u16*)(ws);                  // [BT][1536] bf16  201,326,592 B
  u16* h = (u16*)(ws + 201326592);        // [BT][384]  bf16   50,331,648 B
  u16* WqkvT = (u16*)(ws + 251658240);    // [1152][384]
  u16* WpT = (u16*)(ws + 252542976);      // [384][384]
  u16* W1T = (u16*)(ws + 252837888);      // [1536][384]
  u16* W2T = (u16*)(ws + 254017536);      // [384][1536]

  // Weight transposes (bf16 cast), coalesced via LDS tiles.
  qkvT_kernel<<<dim3(2, 12, 6), 256, 0, stream>>>(Wq, WqkvT);
  qkvT_kernel<<<dim3(2, 12, 6), 256, 0, stream>>>(Wk, WqkvT + 384 * 384);
  qkvT_kernel<<<dim3(2, 12, 6), 256, 0, stream>>>(Wv, WqkvT + 2 * 384 * 384);
  wT_kernel<<<dim3(12, 12), 256, 0, stream>>>(Wp, WpT, 384, 384);
  wT_kernel<<<dim3(48, 12), 256, 0, stream>>>(W1, W1T, 384, 1536);
  wT_kernel<<<dim3(12, 48), 256, 0, stream>>>(W2, W2T, 1536, 384);

  // LN1: x -> h (bf16)
  ln_kernel<<<BT / 4, 256, 0, stream>>>(x, g1, be1, h);
  // QKV: h @ Wqkv -> qkv slabs (OUT_MODE=2), gx=9
  gemm_bt<0, 0, 0, 2><<<9 * 512, 256, 0, stream>>>(h, WqkvT, nullptr, nullptr,
                                                   qkv, BT, 1152, 384, 9);
  // Attention, merged: grid (TQ=4, b*h=1536)
  attn_all<<<dim3(4, 1536), 256, 0, stream>>>(qkv, attnout);
  // Proj + bias + residual(x) -> d_out (fp32), gx=3
  gemm_bt<1, 1, 0, 0><<<3 * 512, 256, 0, stream>>>(attnout, WpT, bp, x, out,
                                                   BT, 384, 384, 3);
  // LN2: d_out -> h (bf16)
  ln_kernel<<<BT / 4, 256, 0, stream>>>(out, g2, be2, h);
  // FFN1 + bias + relu -> ff1 (bf16), gx=12
  gemm_bt<1, 0, 1, 1><<<12 * 512, 256, 0, stream>>>(h, W1T, b1, nullptr, ff1,
                                                    BT, 1536, 384, 12);
  // FFN2 + bias + residual(d_out) -> d_out (fp32), gx=3
  gemm_bt<1, 1, 0, 0><<<3 * 512, 256, 0, stream>>>(ff1, W2T, b2, out, out,
                                                   BT, 384, 1536, 3);
}

// Round 4
// 831.970 us; speedup vs baseline: 1.0179x; 1.0179x over previous
//
#include <hip/hip_runtime.h>
#include <hip/hip_bf16.h>

// ---------------------------------------------------------------------------
// TransformerBlock on MI355X (gfx950), bf16 MFMA pipeline. Round 3:
//  - GEMM K-loop restructured (AITER-style): global_load -> VGPR -> ds_write,
//    raw `s_waitcnt lgkmcnt(0); s_barrier` (no vmcnt drain at barriers!).
//    Loads for tile k+1 stay in flight across the barrier; the only vm wait
//    is the compiler-inserted one at the ds_write late in iter k.
//    (R2 post-mortem: __syncthreads() drains vmcnt(0), so gl2lds prefetch
//    was waited on in the SAME iteration it was issued -> no overlap.)
//  - XOR-swizzled LDS layout kept (R1/R2 measured SQ_LDS_BANK_CONFLICT = 0).
//  - LN / transposes / attention unchanged from R2.
// ---------------------------------------------------------------------------

typedef __attribute__((ext_vector_type(8))) short bf16x8;
typedef __attribute__((ext_vector_type(4))) float f32x4;
typedef unsigned short u16;
typedef unsigned int u32;

#define MFMA16(a, b, c) __builtin_amdgcn_mfma_f32_16x16x32_bf16((a), (b), (c), 0, 0, 0)

// LDS-only barrier: wait for own DS ops, then s_barrier. Does NOT drain vmcnt.
#define LDS_BARRIER() asm volatile("s_waitcnt lgkmcnt(0)\n\ts_barrier" ::: "memory")

__device__ __forceinline__ u16 f2bf(float f) {
  __hip_bfloat16 h = __float2bfloat16(f);
  return *(u16*)&h;
}
__device__ __forceinline__ float bf2f(u16 u) {
  __hip_bfloat16 h;
  *(u16*)&h = u;
  return __bfloat162float(h);
}
__device__ __forceinline__ u32 pack2(float lo, float hi) {
  return (u32)f2bf(lo) | ((u32)f2bf(hi) << 16);
}

// Swizzled slot for chunk (row r, 16B-chunk c) of a 128x32 bf16 tile.
// Superrow = 2 rows = 8 chunks (128 B); XOR-8 within superrow.
__device__ __forceinline__ int sw_slot(int r, int c) {
  return (r >> 1) * 8 + ((((r & 1) << 2) | c) ^ ((r >> 1) & 7));
}

// ---------------------------------------------------------------------------
// GEMM: out[M][N] = A[M][K] (bf16) * Bt[N][K]^T (bf16)  [+bias] [relu] [+res]
// OUT_MODE: 0 = fp32 row-major, 1 = bf16 row-major, 2 = bf16 qkv slabs
// 1-D grid; XCD swizzle: xcd = bid&7 owns a contiguous M-chunk, n fastest.
// ---------------------------------------------------------------------------
template <int HAS_BIAS, int HAS_RES, int RELU, int OUT_MODE>
__global__ __launch_bounds__(256) void gemm_bt(const u16* __restrict__ A,
                                               const u16* __restrict__ Bt,
                                               const float* __restrict__ bias,
                                               const float* res, void* outp,
                                               int M, int N, int K, int gx) {
  __shared__ __attribute__((aligned(16))) u16 As[2][4096];
  __shared__ __attribute__((aligned(16))) u16 Bs[2][4096];
  const int bid = blockIdx.x;
  const int s = bid >> 3, xcd = bid & 7;
  const int gy8 = gridDim.x / (8 * gx);
  const int nI = s % gx, mC = s / gx;
  const int m0 = (xcd * gy8 + mC) * 128, n0 = nI * 128;
  const int w = threadIdx.x >> 6, l = threadIdx.x & 63;
  const int lm = l & 15, quad = l >> 4;
  const int wm = (w >> 1) * 64, wn = (w & 1) * 64;

  // Staging: thread owns chunks ci0 = w*128 + l, ci1 = ci0 + 64 (per matrix).
  // chunk -> (row, col-chunk): r = ci>>2, c = ci&3  (4 x 16B chunks per row).
  // ds_write bank group = (l&7) ^ ((l>>3)&7): uniform across banks.
  const int ci0 = w * 128 + l, ci1 = ci0 + 64;
  const int r0 = ci0 >> 2, c0 = ci0 & 3;
  const int r1 = ci1 >> 2, c1 = ci1 & 3;
  const u16* Ag0 = A + (size_t)(m0 + r0) * K + c0 * 8;
  const u16* Ag1 = A + (size_t)(m0 + r1) * K + c1 * 8;
  const u16* Bg0 = Bt + (size_t)(n0 + r0) * K + c0 * 8;
  const u16* Bg1 = Bt + (size_t)(n0 + r1) * K + c1 * 8;
  const int s0 = sw_slot(r0, c0) * 8, s1 = sw_slot(r1, c1) * 8;

  // Fragment LDS element offsets (constant across K).
  int afo[4], bfo[4];
#pragma unroll
  for (int i = 0; i < 4; ++i) afo[i] = sw_slot(wm + i * 16 + lm, quad) * 8;
#pragma unroll
  for (int j = 0; j < 4; ++j) bfo[j] = sw_slot(wn + j * 16 + lm, quad) * 8;

  f32x4 acc[4][4];
#pragma unroll
  for (int i = 0; i < 4; ++i)
#pragma unroll
    for (int j = 0; j < 4; ++j) acc[i][j] = 0.f;

  const int nk = K >> 5;
  // Prologue: tile 0 -> regs -> LDS buf 0.
  bf16x8 ra0 = *(const bf16x8*)Ag0, ra1 = *(const bf16x8*)Ag1;
  bf16x8 rb0 = *(const bf16x8*)Bg0, rb1 = *(const bf16x8*)Bg1;
  *(bf16x8*)&As[0][s0] = ra0;
  *(bf16x8*)&As[0][s1] = ra1;
  *(bf16x8*)&Bs[0][s0] = rb0;
  *(bf16x8*)&Bs[0][s1] = rb1;
  LDS_BARRIER();

  for (int k = 0; k < nk; ++k) {
    const int cb = k & 1;
    const bool more = (k + 1 < nk);
    if (more) {
      const int go = (k + 1) * 32;
      ra0 = *(const bf16x8*)(Ag0 + go);
      ra1 = *(const bf16x8*)(Ag1 + go);
      rb0 = *(const bf16x8*)(Bg0 + go);
      rb1 = *(const bf16x8*)(Bg1 + go);
    }
    bf16x8 af[4], bfb[4];
#pragma unroll
    for (int i = 0; i < 4; ++i) af[i] = *(const bf16x8*)&As[cb][afo[i]];
#pragma unroll
    for (int j = 0; j < 4; ++j) bfb[j] = *(const bf16x8*)&Bs[cb][bfo[j]];
#pragma unroll
    for (int i = 0; i < 4; ++i)
#pragma unroll
      for (int j = 0; j < 4; ++j) acc[i][j] = MFMA16(af[i], bfb[j], acc[i][j]);
    if (more) {
      const int nb = cb ^ 1;
      // Compiler inserts the vmcnt wait here (for the loads issued above) --
      // one full tile of ds_read+MFMA sits between issue and wait.
      *(bf16x8*)&As[nb][s0] = ra0;
      *(bf16x8*)&As[nb][s1] = ra1;
      *(bf16x8*)&Bs[nb][s0] = rb0;
      *(bf16x8*)&Bs[nb][s1] = rb1;
      LDS_BARRIER();
    }
  }

  // Epilogue. C/D layout (m89-verified): col = lane&15, row = quad*4 + reg.
#pragma unroll
  for (int i = 0; i < 4; ++i) {
#pragma unroll
    for (int j = 0; j < 4; ++j) {
      int col = n0 + wn + j * 16 + lm;
      float bs = HAS_BIAS ? bias[col] : 0.f;
#pragma unroll
      for (int r = 0; r < 4; ++r) {
        int row = m0 + wm + i * 16 + quad * 4 + r;
        float v = acc[i][j][r] + bs;
        if (RELU) v = fmaxf(v, 0.f);
        if (HAS_RES) v += res[(size_t)row * N + col];
        if (OUT_MODE == 0) {
          ((float*)outp)[(size_t)row * N + col] = v;
        } else if (OUT_MODE == 1) {
          ((u16*)outp)[(size_t)row * N + col] = f2bf(v);
        } else {  // qkv slab layout [sel*6+h][BT][64]
          int sel = col / 384;
          int rem = col - sel * 384;
          int hh = rem >> 6, dd = rem & 63;
          ((u16*)outp)[((size_t)(sel * 6 + hh) * 65536 + row) * 64 + dd] = f2bf(v);
        }
      }
    }
  }
}

// ---------------------------------------------------------------------------
// LayerNorm: one wave per 384-elem row, 4 rows per block, 6 elems/lane.
// ---------------------------------------------------------------------------
__global__ __launch_bounds__(256) void ln_kernel(const float* __restrict__ x,
                                                 const float* __restrict__ g,
                                                 const float* __restrict__ be,
                                                 u16* __restrict__ out) {
  int row = blockIdx.x * 4 + (threadIdx.x >> 6);
  int l = threadIdx.x & 63;
  const float2* xr = (const float2*)(x + (size_t)row * 384 + l * 6);
  float2 t0 = xr[0], t1 = xr[1], t2 = xr[2];
  float v[6] = {t0.x, t0.y, t1.x, t1.y, t2.x, t2.y};
  float s = 0.f;
#pragma unroll
  for (int i = 0; i < 6; ++i) s += v[i];
#pragma unroll
  for (int o = 1; o < 64; o <<= 1) s += __shfl_xor(s, o, 64);
  float mu = s * (1.f / 384.f);
  float var = 0.f;
#pragma unroll
  for (int i = 0; i < 6; ++i) {
    float d = v[i] - mu;
    var += d * d;
  }
#pragma unroll
  for (int o = 1; o < 64; o <<= 1) var += __shfl_xor(var, o, 64);
  float rs = rsqrtf(var * (1.f / 384.f) + 1e-5f);
  const float2* gg = (const float2*)(g + l * 6);
  const float2* bb = (const float2*)(be + l * 6);
  float2 g0 = gg[0], g1 = gg[1], g2 = gg[2];
  float2 b0 = bb[0], b1 = bb[1], b2 = bb[2];
  float gv[6] = {g0.x, g0.y, g1.x, g1.y, g2.x, g2.y};
  float bv[6] = {b0.x, b0.y, b1.x, b1.y, b2.x, b2.y};
  float o_[6];
#pragma unroll
  for (int i = 0; i < 6; ++i) o_[i] = (v[i] - mu) * rs * gv[i] + bv[i];
  u32* orow = (u32*)(out + (size_t)row * 384 + l * 6);
  orow[0] = pack2(o_[0], o_[1]);
  orow[1] = pack2(o_[2], o_[3]);
  orow[2] = pack2(o_[4], o_[5]);
}

// ---------------------------------------------------------------------------
// Coalesced transposes via LDS 32x33 tiles (fp32 -> bf16).
// ---------------------------------------------------------------------------
__global__ __launch_bounds__(256) void wT_kernel(const float* __restrict__ in,
                                                 u16* __restrict__ out, int K,
                                                 int N) {
  __shared__ float tile[32][33];
  int n0 = blockIdx.x * 32, k0 = blockIdx.y * 32;
  int tx = threadIdx.x & 31, ty = threadIdx.x >> 5;
#pragma unroll
  for (int i = 0; i < 4; ++i)
    tile[ty + i * 8][tx] = in[(size_t)(k0 + ty + i * 8) * N + n0 + tx];
  __syncthreads();
#pragma unroll
  for (int i = 0; i < 4; ++i)
    out[(size_t)(n0 + ty + i * 8) * K + k0 + tx] = f2bf(tile[tx][ty + i * 8]);
}

// qkvT: W [6][384][64] -> out [(h*64+d)][384]. Grid (2, 12, 6), block 256.
__global__ __launch_bounds__(256) void qkvT_kernel(const float* __restrict__ W,
                                                   u16* __restrict__ out) {
  __shared__ float tile[32][33];
  int h = blockIdx.z;
  const float* in = W + (size_t)h * 384 * 64;
  u16* o = out + (size_t)h * 64 * 384;
  int n0 = blockIdx.x * 32, k0 = blockIdx.y * 32;
  int tx = threadIdx.x & 31, ty = threadIdx.x >> 5;
#pragma unroll
  for (int i = 0; i < 4; ++i)
    tile[ty + i * 8][tx] = in[(size_t)(k0 + ty + i * 8) * 64 + n0 + tx];
  __syncthreads();
#pragma unroll
  for (int i = 0; i < 4; ++i)
    o[(size_t)(n0 + ty + i * 8) * 384 + k0 + tx] = f2bf(tile[tx][ty + i * 8]);
}

// ---------------------------------------------------------------------------
// Attention. qkv slabs: Q = slab h, K = slab 6+h, V = slab 12+h, each
// [65536][64]. One merged kernel, TQ = blockIdx.x.
// ---------------------------------------------------------------------------
template <int TQ>
__device__ __forceinline__ void attn_body(const u16* __restrict__ qkv,
                                          u16* __restrict__ attnout,
                                          unsigned char* smx) {
  constexpr int NFULL = (TQ + 1) * 64;  // causal: cols 0..NFULL-1
  constexpr int NJ = NFULL / 16;
  constexpr int KSTEPS = NFULL / 32;
  int bh = blockIdx.y;
  int h = bh % 6, b = bh / 6;
  int tid = threadIdx.x;
  int w = tid >> 6, l = tid & 63;
  int lm = l & 15, quad = l >> 4;

  u16* Qs = (u16*)smx;            // [64][72]   phase 1
  u16* Ks = (u16*)(smx + 9216);   // [256][72]  phase 1
  u16* P = (u16*)smx;             // [64][256]  phase 2 (aliases Qs + Ks head)
  u16* Vt = (u16*)(smx + 32768);  // [64][256]  phase 2 (aliases Ks tail)

  const u16* Qg = qkv + ((size_t)h * 65536 + b * 256 + TQ * 64) * 64;
  const u16* Kg = qkv + ((size_t)(6 + h) * 65536 + b * 256) * 64;
  const u16* Vg = qkv + ((size_t)(12 + h) * 65536 + b * 256) * 64;

  for (int i = tid; i < 64 * 8; i += 256) {
    int r = i >> 3, cs = i & 7;
    *(bf16x8*)&Qs[r * 72 + cs * 8] = *(const bf16x8*)&Qg[r * 64 + cs * 8];
  }
  for (int i = tid; i < NFULL * 8; i += 256) {
    int r = i >> 3, cs = i & 7;
    *(bf16x8*)&Ks[r * 72 + cs * 8] = *(const bf16x8*)&Kg[r * 64 + cs * 8];
  }
  __syncthreads();

  // S = Q K^T ; wave w owns query rows [w*16, w*16+16).
  f32x4 sacc[NJ];
#pragma unroll
  for (int jt = 0; jt < NJ; ++jt) sacc[jt] = 0.f;
#pragma unroll
  for (int kk = 0; kk < 2; ++kk) {
    bf16x8 aq = *(const bf16x8*)&Qs[(w * 16 + lm) * 72 + kk * 32 + quad * 8];
#pragma unroll
    for (int jt = 0; jt < NJ; ++jt) {
      bf16x8 bk = *(const bf16x8*)&Ks[(jt * 16 + lm) * 72 + kk * 32 + quad * 8];
      sacc[jt] = MFMA16(aq, bk, sacc[jt]);
    }
  }
  __syncthreads();  // Qs/Ks reads done; P/Vt writes may begin.

  // Softmax in registers; 1/sqrt(64) folded into the exp argument.
  int trow = TQ * 64 + w * 16 + quad * 4;
  float inv_l[4];
#pragma unroll
  for (int reg = 0; reg < 4; ++reg) {
    float m_ = -3.0e38f;
#pragma unroll
    for (int jt = 0; jt < NJ; ++jt) {
      int col = jt * 16 + lm;
      if (col <= trow + reg) m_ = fmaxf(m_, sacc[jt][reg]);
    }
#pragma unroll
    for (int o = 1; o < 16; o <<= 1) m_ = fmaxf(m_, __shfl_xor(m_, o, 16));
    float s_ = 0.f;
#pragma unroll
    for (int jt = 0; jt < NJ; ++jt) {
      int col = jt * 16 + lm;
      float pv = (col <= trow + reg) ? __expf(0.125f * (sacc[jt][reg] - m_)) : 0.f;
      sacc[jt][reg] = pv;
      s_ += pv;
    }
#pragma unroll
    for (int o = 1; o < 16; o <<= 1) s_ += __shfl_xor(s_, o, 16);
    inv_l[reg] = 1.f / s_;
  }
#pragma unroll
  for (int jt = 0; jt < NJ; ++jt) {
#pragma unroll
    for (int reg = 0; reg < 4; ++reg) {
      int m = w * 16 + quad * 4 + reg;
      int col = jt * 16 + lm;
      P[m * 256 + (col ^ ((m & 7) * 8))] = f2bf(sacc[jt][reg] * inv_l[reg]);
    }
  }
  for (int i = tid; i < NFULL * 8; i += 256) {
    int sr = i >> 3, cs = i & 7;
    bf16x8 vv = *(const bf16x8*)&Vg[sr * 64 + cs * 8];
#pragma unroll
    for (int j = 0; j < 8; ++j) {
      int d = cs * 8 + j;
      Vt[d * 256 + (sr ^ ((d & 7) * 8))] = (u16)vv[j];
    }
  }
  __syncthreads();

  // O = P V.
  f32x4 oacc[4];
#pragma unroll
  for (int jt = 0; jt < 4; ++jt) oacc[jt] = 0.f;
#pragma unroll
  for (int ks = 0; ks < KSTEPS; ++ks) {
    int m = w * 16 + lm;
    int kc = ks * 32 + quad * 8;
    bf16x8 ap = *(const bf16x8*)&P[m * 256 + (kc ^ ((m & 7) * 8))];
#pragma unroll
    for (int jt = 0; jt < 4; ++jt) {
      int n = jt * 16 + lm;
      bf16x8 bv = *(const bf16x8*)&Vt[n * 256 + (kc ^ ((n & 7) * 8))];
      oacc[jt] = MFMA16(ap, bv, oacc[jt]);
    }
  }
  u16* Og = attnout + ((size_t)(b * 256 + TQ * 64)) * 384 + h * 64;
#pragma unroll
  for (int jt = 0; jt < 4; ++jt)
#pragma unroll
    for (int r = 0; r < 4; ++r)
      Og[(size_t)(w * 16 + quad * 4 + r) * 384 + jt * 16 + lm] = f2bf(oacc[jt][r]);
}

__global__ __launch_bounds__(256) void attn_all(const u16* __restrict__ qkv,
                                                u16* __restrict__ attnout) {
  __shared__ __attribute__((aligned(16))) unsigned char smx[65536];
  switch (blockIdx.x) {
    case 0: attn_body<0>(qkv, attnout, smx); break;
    case 1: attn_body<1>(qkv, attnout, smx); break;
    case 2: attn_body<2>(qkv, attnout, smx); break;
    default: attn_body<3>(qkv, attnout, smx); break;
  }
}

// ---------------------------------------------------------------------------
extern "C" void kernel_launch(void* const* d_in, const int* in_sizes, int n_in,
                              void* d_out, int out_size, void* d_ws, size_t ws_size,
                              hipStream_t stream) {
  const float* x = (const float*)d_in[0];
  const float* Wq = (const float*)d_in[1];
  const float* Wk = (const float*)d_in[2];
  const float* Wv = (const float*)d_in[3];
  const float* Wp = (const float*)d_in[4];
  const float* bp = (const float*)d_in[5];
  const float* W1 = (const float*)d_in[6];
  const float* b1 = (const float*)d_in[7];
  const float* W2 = (const float*)d_in[8];
  const float* b2 = (const float*)d_in[9];
  const float* g1 = (const float*)d_in[10];
  const float* be1 = (const float*)d_in[11];
  const float* g2 = (const float*)d_in[12];
  const float* be2 = (const float*)d_in[13];
  float* out = (float*)d_out;

  const int BT = 65536;  // 256*256
  char* ws = (char*)d_ws;
  u16* qkv = (u16*)(ws);                  // 18 slabs [BT][64] = 150,994,944 B
  u16* attnout = (u16*)(ws + 150994944);  // [BT][384]  bf16   50,331,648 B
  u16* ff1 = (u16*)(ws);                  // [BT][1536] bf16  201,326,592 B
  u16* h = (u16*)(ws + 201326592);        // [BT][384]  bf16   50,331,648 B
  u16* WqkvT = (u16*)(ws + 251658240);    // [1152][384]
  u16* WpT = (u16*)(ws + 252542976);      // [384][384]
  u16* W1T = (u16*)(ws + 252837888);      // [1536][384]
  u16* W2T = (u16*)(ws + 254017536);      // [384][1536]

  // Weight transposes (bf16 cast), coalesced via LDS tiles.
  qkvT_kernel<<<dim3(2, 12, 6), 256, 0, stream>>>(Wq, WqkvT);
  qkvT_kernel<<<dim3(2, 12, 6), 256, 0, stream>>>(Wk, WqkvT + 384 * 384);
  qkvT_kernel<<<dim3(2, 12, 6), 256, 0, stream>>>(Wv, WqkvT + 2 * 384 * 384);
  wT_kernel<<<dim3(12, 12), 256, 0, stream>>>(Wp, WpT, 384, 384);
  wT_kernel<<<dim3(48, 12), 256, 0, stream>>>(W1, W1T, 384, 1536);
  wT_kernel<<<dim3(12, 48), 256, 0, stream>>>(W2, W2T, 1536, 384);

  // LN1: x -> h (bf16)
  ln_kernel<<<BT / 4, 256, 0, stream>>>(x, g1, be1, h);
  // QKV: h @ Wqkv -> qkv slabs (OUT_MODE=2), gx=9
  gemm_bt<0, 0, 0, 2><<<9 * 512, 256, 0, stream>>>(h, WqkvT, nullptr, nullptr,
                                                   qkv, BT, 1152, 384, 9);
  // Attention, merged: grid (TQ=4, b*h=1536)
  attn_all<<<dim3(4, 1536), 256, 0, stream>>>(qkv, attnout);
  // Proj + bias + residual(x) -> d_out (fp32), gx=3
  gemm_bt<1, 1, 0, 0><<<3 * 512, 256, 0, stream>>>(attnout, WpT, bp, x, out,
                                                   BT, 384, 384, 3);
  // LN2: d_out -> h (bf16)
  ln_kernel<<<BT / 4, 256, 0, stream>>>(out, g2, be2, h);
  // FFN1 + bias + relu -> ff1 (bf16), gx=12
  gemm_bt<1, 0, 1, 1><<<12 * 512, 256, 0, stream>>>(h, W1T, b1, nullptr, ff1,
                                                    BT, 1536, 384, 12);
  // FFN2 + bias + residual(d_out) -> d_out (fp32), gx=3
  gemm_bt<1, 1, 0, 0><<<3 * 512, 256, 0, stream>>>(ff1, W2T, b2, out, out,
                                                   BT, 384, 1536, 3);
}